// Round 15
// baseline (538.402 us; speedup 1.0000x reference)
//
#include <hip/hip_runtime.h>

#define B_ 256
#define D_ 128
#define T_ 1024
#define H_ 64
#define G_ 192
#define TILE_T 64
#define NTILES (T_ / TILE_T)   // 16
#define XGS 65                 // ring t-stride: 65%32=1 -> 2-way max (free)
#define KC 16                  // producer k-chunk (16 -> w_s fits LDS budget)
#define WS 194                 // w_s g-stride

typedef float f32x4 __attribute__((ext_vector_type(4)));
typedef float f32x2 __attribute__((ext_vector_type(2)));
typedef unsigned long long u64;

// Fused GRU, 1 launch. Block = 1 batch row, 7 waves (448 thr), 1 block/CU.
//   waves 0,1,2 : scan, one gate-DOT each (64 f32 weight regs -> no spill,
//                 proven r8/r10). pk_fma dots (64-cyc issue). Publish via
//                 writer-duplicated pair slots: each wave writes {tag|dot}
//                 into BOTH readers' contiguous 16B pairs -> poll is one
//                 volatile pair-load, publishes off-critical-path.
//   waves 3..6  : register-tiled GEMM producers -> LDS ring, pk_fma
//                 (f32x2 accs) -> burst VALU issue halved (contention is
//                 the r8..r13 invariant ~450cyc: scan shares SIMD slots
//                 with producer FMA bursts; readlane-dot == LDS-dot both
//                 at ~1200cyc/step proved it's issue-side, not DS-side).
// r14 LDS overflow (164,376 > 163,840) fixed via KC 32->16 (w_s -12.4KB);
// producers have 4-5x slack so 8 extra psyncs/tile stay hidden.
__global__ __launch_bounds__(448, 2) void gru_fused(
    const float* __restrict__ lat, const float* __restrict__ hidden_init,
    const float* __restrict__ W_ih, const float* __restrict__ W_hh,
    const float* __restrict__ b_ih, const float* __restrict__ b_hh,
    const float* __restrict__ head_w, const float* __restrict__ head_b,
    float* __restrict__ out)
{
    __shared__ float xg_s[2][G_ * XGS];     // 99,840 B ring [slot][g*XGS+t]
    __shared__ float lat_s[D_ * TILE_T];    // 32,768 B [d][t]
    __shared__ float w_s[KC * WS];          // 12,416 B [kk][g]
    __shared__ float h_priv[3][H_];         // per-scan-wave private h copy
    __shared__ u64  pairs[3][2][H_][2];     // 6,144 B [reader][parity][lane][2]
    __shared__ unsigned prod_done[2], cons_done[2], pbar;

    const int b    = blockIdx.x;
    const int tid  = threadIdx.x;
    const int lane = tid & 63;
    const int wid  = tid >> 6;

    if (tid < 2) { prod_done[tid] = 0u; cons_done[tid] = 0u; }
    if (tid == 2) pbar = 0u;
    for (int i = tid; i < 3 * 2 * H_ * 2; i += 448) ((u64*)pairs)[i] = 0ull;
    __syncthreads();   // only workgroup barrier (all 7 waves present)

    if (wid < 3) {
        // =============== scan: one gate-dot per wave, 1 hop/step ===============
        __builtin_amdgcn_s_setprio(2);
        const int j   = lane;
        const int row = wid * H_ + j;        // rows: r 0..63 | z 64..127 | n 128..191
        f32x4 w4[16];
        {
            const f32x4* W = (const f32x4*)(W_hh + (size_t)row * H_);
#pragma unroll
            for (int q = 0; q < 16; ++q) w4[q] = W[q];
        }
        asm volatile("" : "+v"(w4[0]), "+v"(w4[1]), "+v"(w4[2]), "+v"(w4[3]),
                          "+v"(w4[4]), "+v"(w4[5]), "+v"(w4[6]), "+v"(w4[7]),
                          "+v"(w4[8]), "+v"(w4[9]), "+v"(w4[10]), "+v"(w4[11]),
                          "+v"(w4[12]), "+v"(w4[13]), "+v"(w4[14]), "+v"(w4[15]));
        const float bias = b_hh[row];
        const float hw   = (wid == 0) ? head_w[j] : 0.f;
        const int o1 = (wid == 0) ? 1 : 0;
        const int o2 = (wid == 2) ? 1 : 2;
        // my slot index inside reader r's pair: 0 if I'm the smaller writer id
        const int i1 = (wid < 3 - o1 - wid) ? 0 : 1;
        const int i2 = (wid < 3 - o2 - wid) ? 0 : 1;
        volatile u64* wr1 = &pairs[o1][0][j][i1];
        volatile u64* wr2 = &pairs[o2][0][j][i2];
        volatile u64* rd  = &pairs[wid][0][j][0];
        const int pstride = 2 * H_;          // u64s between parity planes
        float h = hidden_init[b * H_ + j];
        unsigned sg = 0;

        for (int k = 0; k < NTILES; ++k) {
            const int s = k & 1;
            const unsigned tgt = 4u * (unsigned)((k >> 1) + 1);   // 4 producers
            while (__hip_atomic_load(&prod_done[s], __ATOMIC_ACQUIRE,
                                     __HIP_MEMORY_SCOPE_WORKGROUP) < tgt)
                __builtin_amdgcn_s_sleep(1);
            const float* xr_p = &xg_s[s][(size_t)j * XGS];
            const float* xz_p = &xg_s[s][(size_t)(H_ + j) * XGS];
            const float* xn_p = &xg_s[s][(size_t)(2 * H_ + j) * XGS];

#pragma unroll 2
            for (int t = 0; t < TILE_T; ++t, ++sg) {
                const int par = (int)(sg & 1u);
                h_priv[wid][j] = h;                  // within-wave DS order
                float xr = xr_p[t], xz = xz_p[t], xn = xn_p[t];
                const f32x4* h4 = (const f32x4*)h_priv[wid];
                f32x4 a4 = {0.f, 0.f, 0.f, 0.f};
#pragma unroll
                for (int q = 0; q < 16; ++q)
                    a4 += w4[q] * h4[q];             // v_pk_fma_f32 x2
                float a = ((a4.x + a4.y) + (a4.z + a4.w)) + bias;
                const unsigned want = sg + 1;

                // publish my dot to BOTH readers' pair slots (off-path)
                u64 pk = ((u64)want << 32) | (u64)__builtin_bit_cast(unsigned, a);
                wr1[par * pstride] = pk;
                wr2[par * pstride] = pk;
                // poll my own contiguous pair (one ds_read2-able access)
                u64 v1, v2;
                do {
                    v1 = rd[par * pstride + 0];
                    v2 = rd[par * pstride + 1];
                } while ((unsigned)(v1 >> 32) != want || (unsigned)(v2 >> 32) != want);
                float b1 = __builtin_bit_cast(float, (unsigned)v1);
                float b2 = __builtin_bit_cast(float, (unsigned)v2);

                // pair order is (smaller gate id, larger): map to (ar,az,an)
                float ar, az, an;
                if (wid == 0)      { ar = a;  az = b1; an = b2; }   // pair=(1,2)
                else if (wid == 1) { ar = b1; az = a;  an = b2; }   // pair=(0,2)
                else               { ar = b1; az = b2; an = a;  }   // pair=(0,1)

                float r   = __builtin_amdgcn_rcpf(1.f + __expf(-(xr + ar)));
                float z   = __builtin_amdgcn_rcpf(1.f + __expf(-(xz + az)));
                float pre = xn + r * an;
                float n   = fmaf(-2.f, __builtin_amdgcn_rcpf(__expf(2.f * pre) + 1.f), 1.f);
                h = fmaf(z, h - n, n);               // (1-z)n + zh
            }
            if (lane == 0)   // all 3 scan waves release; producers wait 3m
                __hip_atomic_fetch_add(&cons_done[s], 1u, __ATOMIC_RELEASE,
                                       __HIP_MEMORY_SCOPE_WORKGROUP);
        }

        if (wid == 0) {   // all waves hold identical final h
            out[B_ + b * H_ + j] = h;
            float v = h * hw;
#pragma unroll
            for (int off = 32; off > 0; off >>= 1) v += __shfl_down(v, off);
            if (lane == 0) out[b] = v + head_b[0];
        }
    } else {
        // ========== producers: register-tiled GEMM, pk_fma accs ==========
        const int p  = tid - 192;        // 0..255
        const int tx = p & 7;            // t-sub: t = tx*8 + 2*jj + hh
        const int gy = p >> 3;           // g-sub: g = gy*6 + i
        const float* latb = lat + (size_t)b * (D_ * T_);
        unsigned phase = 0;

        auto psync = [&]() {
            if ((p & 63) == 0)
                __hip_atomic_fetch_add(&pbar, 1u, __ATOMIC_RELEASE,
                                       __HIP_MEMORY_SCOPE_WORKGROUP);
            ++phase;
            while (__hip_atomic_load(&pbar, __ATOMIC_ACQUIRE,
                                     __HIP_MEMORY_SCOPE_WORKGROUP) < 4u * phase) {}
        };

        float bias[6];
#pragma unroll
        for (int i = 0; i < 6; ++i) bias[i] = b_ih[gy * 6 + i];

        for (int k = 0; k < NTILES; ++k) {
            const int s = k & 1, m = k >> 1;
            if (m >= 1) {
                while (__hip_atomic_load(&cons_done[s], __ATOMIC_ACQUIRE,
                                         __HIP_MEMORY_SCOPE_WORKGROUP) < 3u * (unsigned)m)
                    __builtin_amdgcn_s_sleep(1);
            }
            psync();   // all producers past previous tile's lat_s/w_s

            // stage lat tile [d][t] (coalesced)
#pragma unroll
            for (int i = 0; i < 32; ++i) {
                int f = p + 256 * i;           // f = d*64 + t
                int d = f >> 6, t = f & 63;
                lat_s[f] = latb[(size_t)d * T_ + k * TILE_T + t];
            }

            f32x2 acc2[4][6];                  // [t-pair][g] packed accs
#pragma unroll
            for (int jj = 0; jj < 4; ++jj)
#pragma unroll
                for (int i = 0; i < 6; ++i) acc2[jj][i] = f32x2{0.f, 0.f};

            for (int kc = 0; kc < D_; kc += KC) {
                psync();   // lat_s staged / previous w_s consumed
#pragma unroll
                for (int i = 0; i < (G_ * KC) / 256; ++i) {   // 12/thread
                    int f = p + 256 * i;
                    int g = f >> 4, kk = f & 15;
                    w_s[kk * WS + g] = W_ih[(size_t)g * D_ + kc + kk];
                }
                psync();   // w_s ready
#pragma unroll 4
                for (int kk = 0; kk < KC; ++kk) {
                    f32x4 l0 = *(const f32x4*)&lat_s[(kc + kk) * 64 + tx * 8];
                    f32x4 l1 = *(const f32x4*)&lat_s[(kc + kk) * 64 + tx * 8 + 4];
                    f32x2 lv2[4] = {f32x2{l0.x, l0.y}, f32x2{l0.z, l0.w},
                                    f32x2{l1.x, l1.y}, f32x2{l1.z, l1.w}};
                    float2 w0 = *(const float2*)&w_s[kk * WS + gy * 6];
                    float2 w1 = *(const float2*)&w_s[kk * WS + gy * 6 + 2];
                    float2 w2 = *(const float2*)&w_s[kk * WS + gy * 6 + 4];
                    float wv[6] = {w0.x, w0.y, w1.x, w1.y, w2.x, w2.y};
#pragma unroll
                    for (int jj = 0; jj < 4; ++jj)
#pragma unroll
                        for (int i = 0; i < 6; ++i)
                            acc2[jj][i] += lv2[jj] * f32x2{wv[i], wv[i]};  // v_pk_fma_f32
                }
            }

            // write tile to ring slot
            float* xs = xg_s[s];
#pragma unroll
            for (int i = 0; i < 6; ++i)
#pragma unroll
                for (int jj = 0; jj < 4; ++jj) {
                    xs[(size_t)(gy * 6 + i) * XGS + tx * 8 + 2 * jj + 0] = acc2[jj][i].x + bias[i];
                    xs[(size_t)(gy * 6 + i) * XGS + tx * 8 + 2 * jj + 1] = acc2[jj][i].y + bias[i];
                }

            if ((p & 63) == 0)
                __hip_atomic_fetch_add(&prod_done[s], 1u, __ATOMIC_RELEASE,
                                       __HIP_MEMORY_SCOPE_WORKGROUP);
        }
    }
}

extern "C" void kernel_launch(void* const* d_in, const int* in_sizes, int n_in,
                              void* d_out, int out_size, void* d_ws, size_t ws_size,
                              hipStream_t stream)
{
    const float* lat   = (const float*)d_in[0];
    const float* hid0  = (const float*)d_in[1];
    const float* W_ih  = (const float*)d_in[2];
    const float* W_hh  = (const float*)d_in[3];
    const float* b_ih  = (const float*)d_in[4];
    const float* b_hh  = (const float*)d_in[5];
    const float* headw = (const float*)d_in[6];
    const float* headb = (const float*)d_in[7];
    float* out = (float*)d_out;

    gru_fused<<<dim3(B_), dim3(448), 0, stream>>>(
        lat, hid0, W_ih, W_hh, b_ih, b_hh, headw, headb, out);
}

// Round 16
// 514.535 us; speedup vs baseline: 1.0464x; 1.0464x over previous
//
#include <hip/hip_runtime.h>

#define B_ 256
#define D_ 128
#define T_ 1024
#define H_ 64
#define G_ 192
#define TILE_T 64
#define NTILES (T_ / TILE_T)   // 16
#define XGS 65                 // ring t-stride: 65%32=1 -> 2-way max (free)
#define KC 16                  // producer k-chunk
#define WS 194                 // w_s g-stride

typedef float f32x4 __attribute__((ext_vector_type(4)));
typedef float f32x2 __attribute__((ext_vector_type(2)));
typedef unsigned int u32x4 __attribute__((ext_vector_type(4)));
typedef unsigned long long u64;

// Fused GRU, 1 launch. Block = 1 batch row, 7 waves (448 thr), 1 block/CU.
//   waves 0,1,2 : scan, one gate-DOT each; pointwise replicated; ONE hop.
//                 r16: pairs2[reader][par][AB][lane] -> lane stride 8B
//                 (2-way, free; r15's [lane][2] was 16B stride = 8-way,
//                 conflicts 4.7M->11.2M, the whole regression). Poll is a
//                 single ds_read2_b64 (offset1:64 = 512B AB-plane gap).
//   waves 3..6  : register-tiled GEMM producers -> LDS ring; pk_fma accs;
//                 lat staging via float4/ds_write_b128 (32->8 DS ops/thr).
__global__ __launch_bounds__(448, 2) void gru_fused(
    const float* __restrict__ lat, const float* __restrict__ hidden_init,
    const float* __restrict__ W_ih, const float* __restrict__ W_hh,
    const float* __restrict__ b_ih, const float* __restrict__ b_hh,
    const float* __restrict__ head_w, const float* __restrict__ head_b,
    float* __restrict__ out)
{
    __shared__ float xg_s[2][G_ * XGS];     // 99,840 B ring [slot][g*XGS+t]
    __shared__ float lat_s[D_ * TILE_T];    // 32,768 B [d][t]
    __shared__ float w_s[KC * WS];          // 12,416 B [kk][g]
    __shared__ float h_priv[3][H_];         //    768 B per-scan-wave h copy
    __shared__ u64  pairs2[3][2][2][H_];    //  6,144 B [reader][par][AB][lane]
    __shared__ unsigned prod_done[2], cons_done[2], pbar;

    const int b    = blockIdx.x;
    const int tid  = threadIdx.x;
    const int lane = tid & 63;
    const int wid  = tid >> 6;

    if (tid < 2) { prod_done[tid] = 0u; cons_done[tid] = 0u; }
    if (tid == 2) pbar = 0u;
    for (int i = tid; i < 3 * 2 * 2 * H_; i += 448) ((u64*)pairs2)[i] = 0ull;
    __syncthreads();   // only workgroup barrier (all 7 waves present)

    if (wid < 3) {
        // =============== scan: one gate-dot per wave, 1 hop/step ===============
        __builtin_amdgcn_s_setprio(2);
        const int j   = lane;
        const int row = wid * H_ + j;        // rows: r 0..63 | z 64..127 | n 128..191
        f32x4 w4[16];
        {
            const f32x4* W = (const f32x4*)(W_hh + (size_t)row * H_);
#pragma unroll
            for (int q = 0; q < 16; ++q) w4[q] = W[q];
        }
        asm volatile("" : "+v"(w4[0]), "+v"(w4[1]), "+v"(w4[2]), "+v"(w4[3]),
                          "+v"(w4[4]), "+v"(w4[5]), "+v"(w4[6]), "+v"(w4[7]),
                          "+v"(w4[8]), "+v"(w4[9]), "+v"(w4[10]), "+v"(w4[11]),
                          "+v"(w4[12]), "+v"(w4[13]), "+v"(w4[14]), "+v"(w4[15]));
        const float bias = b_hh[row];
        const float hw   = (wid == 0) ? head_w[j] : 0.f;
        const int o1 = (wid == 0) ? 1 : 0;           // my two readers
        const int o2 = (wid == 2) ? 1 : 2;
        const int i1 = (wid < 3 - o1 - wid) ? 0 : 1; // my AB slot at each reader
        const int i2 = (wid < 3 - o2 - wid) ? 0 : 1;
        volatile u64* wr1_0 = &pairs2[o1][0][i1][j];
        volatile u64* wr1_1 = &pairs2[o1][1][i1][j];
        volatile u64* wr2_0 = &pairs2[o2][0][i2][j];
        volatile u64* wr2_1 = &pairs2[o2][1][i2][j];
        const unsigned rda_0 = (unsigned)(size_t)&pairs2[wid][0][0][j];
        const unsigned rda_1 = (unsigned)(size_t)&pairs2[wid][1][0][j];
        float h = hidden_init[b * H_ + j];

        for (int k = 0; k < NTILES; ++k) {
            const int s = k & 1;
            const unsigned tgt = 4u * (unsigned)((k >> 1) + 1);   // 4 producers
            while (__hip_atomic_load(&prod_done[s], __ATOMIC_ACQUIRE,
                                     __HIP_MEMORY_SCOPE_WORKGROUP) < tgt)
                __builtin_amdgcn_s_sleep(1);
            const float* xr_p = &xg_s[s][(size_t)j * XGS];
            const float* xz_p = &xg_s[s][(size_t)(H_ + j) * XGS];
            const float* xn_p = &xg_s[s][(size_t)(2 * H_ + j) * XGS];
            const unsigned sgk = (unsigned)(k * TILE_T);

#define SCAN_STEP(PAR, TT) do {                                              \
            h_priv[wid][j] = h;                  /* within-wave DS order */  \
            float xr = xr_p[TT], xz = xz_p[TT], xn = xn_p[TT];               \
            const f32x4* h4_ = (const f32x4*)h_priv[wid];                    \
            f32x4 a4 = {0.f, 0.f, 0.f, 0.f};                                 \
            _Pragma("unroll")                                                \
            for (int q = 0; q < 16; ++q) a4 += w4[q] * h4_[q];               \
            float a = ((a4.x + a4.y) + (a4.z + a4.w)) + bias;                \
            const unsigned want = sgk + (TT) + 1u;                           \
            u64 pk = ((u64)want << 32) | (u64)__builtin_bit_cast(unsigned, a);\
            *(PAR ? wr1_1 : wr1_0) = pk;                                     \
            *(PAR ? wr2_1 : wr2_0) = pk;                                     \
            u64 v1, v2;                                                      \
            do {                                                             \
                u32x4 vv;                                                    \
                asm volatile("ds_read2_b64 %0, %1 offset1:64\n\t"            \
                             "s_waitcnt lgkmcnt(0)"                          \
                             : "=v"(vv) : "v"(PAR ? rda_1 : rda_0)           \
                             : "memory");                                    \
                v1 = ((u64)vv.y << 32) | vv.x;                               \
                v2 = ((u64)vv.w << 32) | vv.z;                               \
            } while ((unsigned)(v1 >> 32) != want ||                         \
                     (unsigned)(v2 >> 32) != want);                          \
            float b1 = __builtin_bit_cast(float, (unsigned)v1);              \
            float b2 = __builtin_bit_cast(float, (unsigned)v2);              \
            float ar, az, an;                                                \
            if (wid == 0)      { ar = a;  az = b1; an = b2; }                \
            else if (wid == 1) { ar = b1; az = a;  an = b2; }                \
            else               { ar = b1; az = b2; an = a;  }                \
            float r_  = __builtin_amdgcn_rcpf(1.f + __expf(-(xr + ar)));     \
            float z_  = __builtin_amdgcn_rcpf(1.f + __expf(-(xz + az)));     \
            float pre = xn + r_ * an;                                        \
            float n_  = fmaf(-2.f, __builtin_amdgcn_rcpf(__expf(2.f * pre) + 1.f), 1.f); \
            h = fmaf(z_, h - n_, n_);                                        \
        } while (0)

            for (int t = 0; t < TILE_T; t += 2) {
                SCAN_STEP(0, t);
                SCAN_STEP(1, t + 1);
            }
#undef SCAN_STEP
            if (lane == 0)   // all 3 scan waves release; producers wait 3m
                __hip_atomic_fetch_add(&cons_done[s], 1u, __ATOMIC_RELEASE,
                                       __HIP_MEMORY_SCOPE_WORKGROUP);
        }

        if (wid == 0) {   // all waves hold identical final h
            out[B_ + b * H_ + j] = h;
            float v = h * hw;
#pragma unroll
            for (int off = 32; off > 0; off >>= 1) v += __shfl_down(v, off);
            if (lane == 0) out[b] = v + head_b[0];
        }
    } else {
        // ========== producers: register-tiled GEMM, pk_fma accs ==========
        const int p  = tid - 192;        // 0..255
        const int tx = p & 7;            // t-sub: t = tx*8 + 2*jj + hh
        const int gy = p >> 3;           // g-sub: g = gy*6 + i
        const float* latb = lat + (size_t)b * (D_ * T_);
        unsigned phase = 0;

        auto psync = [&]() {
            if ((p & 63) == 0)
                __hip_atomic_fetch_add(&pbar, 1u, __ATOMIC_RELEASE,
                                       __HIP_MEMORY_SCOPE_WORKGROUP);
            ++phase;
            while (__hip_atomic_load(&pbar, __ATOMIC_ACQUIRE,
                                     __HIP_MEMORY_SCOPE_WORKGROUP) < 4u * phase) {}
        };

        float bias[6];
#pragma unroll
        for (int i = 0; i < 6; ++i) bias[i] = b_ih[gy * 6 + i];

        for (int k = 0; k < NTILES; ++k) {
            const int s = k & 1, m = k >> 1;
            if (m >= 1) {
                while (__hip_atomic_load(&cons_done[s], __ATOMIC_ACQUIRE,
                                         __HIP_MEMORY_SCOPE_WORKGROUP) < 3u * (unsigned)m)
                    __builtin_amdgcn_s_sleep(1);
            }
            psync();   // all producers past previous tile's lat_s/w_s

            // stage lat tile [d][t] via float4 both sides (8 DS ops/thread)
#pragma unroll
            for (int i = 0; i < 8; ++i) {
                int f4 = p + 256 * i;          // [0,2048): f4*4 covers 8192 floats
                int d  = f4 >> 4;
                int t4 = (f4 & 15) * 4;
                f32x4 v = *(const f32x4*)&latb[(size_t)d * T_ + k * TILE_T + t4];
                *(f32x4*)&lat_s[d * 64 + t4] = v;
            }

            f32x2 acc2[4][6];                  // [t-pair][g] packed accs
#pragma unroll
            for (int jj = 0; jj < 4; ++jj)
#pragma unroll
                for (int i = 0; i < 6; ++i) acc2[jj][i] = f32x2{0.f, 0.f};

            for (int kc = 0; kc < D_; kc += KC) {
                psync();   // lat_s staged / previous w_s consumed
#pragma unroll
                for (int i = 0; i < (G_ * KC) / 256; ++i) {   // 12/thread
                    int f = p + 256 * i;
                    int g = f >> 4, kk = f & 15;
                    w_s[kk * WS + g] = W_ih[(size_t)g * D_ + kc + kk];
                }
                psync();   // w_s ready
#pragma unroll 4
                for (int kk = 0; kk < KC; ++kk) {
                    f32x4 l0 = *(const f32x4*)&lat_s[(kc + kk) * 64 + tx * 8];
                    f32x4 l1 = *(const f32x4*)&lat_s[(kc + kk) * 64 + tx * 8 + 4];
                    f32x2 lv2[4] = {f32x2{l0.x, l0.y}, f32x2{l0.z, l0.w},
                                    f32x2{l1.x, l1.y}, f32x2{l1.z, l1.w}};
                    float2 w0 = *(const float2*)&w_s[kk * WS + gy * 6];
                    float2 w1 = *(const float2*)&w_s[kk * WS + gy * 6 + 2];
                    float2 w2 = *(const float2*)&w_s[kk * WS + gy * 6 + 4];
                    float wv[6] = {w0.x, w0.y, w1.x, w1.y, w2.x, w2.y};
#pragma unroll
                    for (int jj = 0; jj < 4; ++jj)
#pragma unroll
                        for (int i = 0; i < 6; ++i)
                            acc2[jj][i] += lv2[jj] * f32x2{wv[i], wv[i]};  // v_pk_fma_f32
                }
            }

            // write tile to ring slot
            float* xs = xg_s[s];
#pragma unroll
            for (int i = 0; i < 6; ++i)
#pragma unroll
                for (int jj = 0; jj < 4; ++jj) {
                    xs[(size_t)(gy * 6 + i) * XGS + tx * 8 + 2 * jj + 0] = acc2[jj][i].x + bias[i];
                    xs[(size_t)(gy * 6 + i) * XGS + tx * 8 + 2 * jj + 1] = acc2[jj][i].y + bias[i];
                }

            if ((p & 63) == 0)
                __hip_atomic_fetch_add(&prod_done[s], 1u, __ATOMIC_RELEASE,
                                       __HIP_MEMORY_SCOPE_WORKGROUP);
        }
    }
}

extern "C" void kernel_launch(void* const* d_in, const int* in_sizes, int n_in,
                              void* d_out, int out_size, void* d_ws, size_t ws_size,
                              hipStream_t stream)
{
    const float* lat   = (const float*)d_in[0];
    const float* hid0  = (const float*)d_in[1];
    const float* W_ih  = (const float*)d_in[2];
    const float* W_hh  = (const float*)d_in[3];
    const float* b_ih  = (const float*)d_in[4];
    const float* b_hh  = (const float*)d_in[5];
    const float* headw = (const float*)d_in[6];
    const float* headb = (const float*)d_in[7];
    float* out = (float*)d_out;

    gru_fused<<<dim3(B_), dim3(448), 0, stream>>>(
        lat, hid0, W_ih, W_hh, b_ih, b_hh, headw, headb, out);
}